// Round 3
// baseline (197.616 us; speedup 1.0000x reference)
//
#include <hip/hip_runtime.h>

#define N_NODES 50000
#define N_EDGES 400000
#define DIM 128
#define BUCKET_BLK ((N_EDGES + 255) / 256)   // 1563
#define FC1_BLK ((N_NODES + 63) / 64)        // 782

typedef unsigned short u16;
typedef unsigned int   u32;
typedef __bf16 v8bf  __attribute__((ext_vector_type(8)));
typedef float  f32x4 __attribute__((ext_vector_type(4)));
typedef u16    u16x8 __attribute__((ext_vector_type(8)));

union BF8 { u16x8 u; v8bf b; };

__device__ __forceinline__ float bf2f(u16 u) {
    union { u32 i; float f; } v; v.i = ((u32)u) << 16; return v.f;
}
__device__ __forceinline__ u16 f2bf(float f) {
    union { float f; u32 i; } v; v.f = f; u32 u = v.i;
    return (u16)((u + 0x7FFFu + ((u >> 16) & 1u)) >> 16);  // RNE
}

// ---------------------------------------------------------------------------
// build + fc1 fused:
//   blocks [0, BUCKET_BLK): per-dst linked-list build:
//     old = atomicExch(head[dst], e); pair[e] = {old, src}
//   blocks [BUCKET_BLK, +FC1_BLK): fc1 MFMA tile, W1 cast fp32->bf16 in-regs.
// ---------------------------------------------------------------------------
__global__ __launch_bounds__(256, 3) void build_fc1_kernel(
    const int* __restrict__ esrc, const int* __restrict__ edst,
    int* __restrict__ head, int2* __restrict__ pairbuf,
    const float* __restrict__ x, const float* __restrict__ W1,
    const float* __restrict__ b1, u16* __restrict__ h)
{
    __shared__ u16 xs[64 * 136];
    const int bid = blockIdx.x;

    if (bid < BUCKET_BLK) {
        int e = bid * 256 + threadIdx.x;
        if (e < N_EDGES) {
            int src = esrc[e], dst = edst[e];
            if ((unsigned)src < N_NODES && (unsigned)dst < N_NODES) {
                int old = atomicExch(&head[dst], e);
                pairbuf[e] = make_int2(old, src);
            }
        }
        return;
    }

    // ---- fc1 tile ----
    const int t = threadIdx.x;
    const int wave = t >> 6, lane = t & 63, quad = lane >> 4, l15 = lane & 15;
    const int ch = wave >> 1, rh = wave & 1;
    const int row0 = (bid - BUCKET_BLK) * 64;

    BF8 barr[4][4];
#pragma unroll
    for (int ct = 0; ct < 4; ++ct)
#pragma unroll
        for (int ks = 0; ks < 4; ++ks) {
            const float* wp = W1 + (size_t)(ch * 64 + ct * 16 + l15) * DIM
                                 + ks * 32 + quad * 8;
            float4 f0 = *(const float4*)wp;
            float4 f1 = *(const float4*)(wp + 4);
            u16x8 p;
            p[0] = f2bf(f0.x); p[1] = f2bf(f0.y); p[2] = f2bf(f0.z); p[3] = f2bf(f0.w);
            p[4] = f2bf(f1.x); p[5] = f2bf(f1.y); p[6] = f2bf(f1.z); p[7] = f2bf(f1.w);
            barr[ct][ks].u = p;
        }

    {
        int srow = t >> 2, k0 = (t & 3) * 32;
        int grow = row0 + srow; if (grow >= N_NODES) grow = N_NODES - 1;
        const float* xp = x + (size_t)grow * DIM + k0;
#pragma unroll
        for (int j = 0; j < 4; ++j) {
            float4 f0 = *(const float4*)(xp + j * 8);
            float4 f1 = *(const float4*)(xp + j * 8 + 4);
            u16x8 p;
            p[0] = f2bf(f0.x); p[1] = f2bf(f0.y); p[2] = f2bf(f0.z); p[3] = f2bf(f0.w);
            p[4] = f2bf(f1.x); p[5] = f2bf(f1.y); p[6] = f2bf(f1.z); p[7] = f2bf(f1.w);
            *(u16x8*)&xs[srow * 136 + k0 + j * 8] = p;
        }
    }

    f32x4 acc[2][4];
#pragma unroll
    for (int ct = 0; ct < 4; ++ct) {
        float bv = b1[ch * 64 + ct * 16 + l15];
        acc[0][ct] = (f32x4){bv, bv, bv, bv};
        acc[1][ct] = (f32x4){bv, bv, bv, bv};
    }
    __syncthreads();

#pragma unroll
    for (int ks = 0; ks < 4; ++ks) {
        BF8 a0, a1;
        a0.u = *(const u16x8*)&xs[(rh * 32 +  0 + l15) * 136 + ks * 32 + quad * 8];
        a1.u = *(const u16x8*)&xs[(rh * 32 + 16 + l15) * 136 + ks * 32 + quad * 8];
#pragma unroll
        for (int ct = 0; ct < 4; ++ct) {
            acc[0][ct] = __builtin_amdgcn_mfma_f32_16x16x32_bf16(
                a0.b, barr[ct][ks].b, acc[0][ct], 0, 0, 0);
            acc[1][ct] = __builtin_amdgcn_mfma_f32_16x16x32_bf16(
                a1.b, barr[ct][ks].b, acc[1][ct], 0, 0, 0);
        }
    }

#pragma unroll
    for (int rt = 0; rt < 2; ++rt)
#pragma unroll
        for (int i = 0; i < 4; ++i) {
            int row = row0 + rh * 32 + rt * 16 + quad * 4 + i;
            if (row < N_NODES) {
#pragma unroll
                for (int ct = 0; ct < 4; ++ct) {
                    int col = ch * 64 + ct * 16 + l15;
                    h[(size_t)row * DIM + col] = f2bf(fmaxf(acc[rt][ct][i], 0.f));
                }
            }
        }
}

// ---------------------------------------------------------------------------
// aggregate + fc2 fused, one 64-node tile per block.
// Phase A: each wave owns 16 nodes = 4 rounds x 4 concurrent quad-chains.
//   A quad's 16 lanes each gather 16B of the 256B h-row; the chain pointer
//   (pairbuf[e].x) is the only serial dependency. 48 chains in flight per CU.
//   Result (mean + residual) goes straight into the LDS tile -> z never
//   touches global memory.
// Phase B: fc2 MFMA from LDS (W2 cast fp32->bf16 in-regs, loaded after chase).
// ---------------------------------------------------------------------------
__global__ __launch_bounds__(256, 3) void agg_fc2_kernel(
    const int* __restrict__ head, const int2* __restrict__ pairbuf,
    const u16* __restrict__ h, const float* __restrict__ W2,
    const float* __restrict__ b2, float* __restrict__ out)
{
    __shared__ u16 xs[64 * 136];
    const int t = threadIdx.x;
    const int wv = t >> 6, lane = t & 63, quad = lane >> 4, l15 = lane & 15;
    const int row0 = blockIdx.x * 64;

    // ---- phase A: chase ----
#pragma unroll 1
    for (int r = 0; r < 4; ++r) {
        const int s = wv * 16 + r * 4 + quad;
        const int n = row0 + s;
        float a[8];
#pragma unroll
        for (int j = 0; j < 8; ++j) a[j] = 0.f;
        int deg = 0;
        u16x8 pk = (u16x8){0, 0, 0, 0, 0, 0, 0, 0};
        if (n < N_NODES) {
            int e = head[n];
            while (e >= 0) {
                int2 p = pairbuf[e];                  // 8B, same addr in quad
                u16x8 v = *(const u16x8*)(h + (size_t)p.y * DIM + l15 * 8);
                e = p.x;                              // only serial dep
                ++deg;
#pragma unroll
                for (int j = 0; j < 8; ++j) a[j] += bf2f(v[j]);
            }
            u16x8 hres = *(const u16x8*)(h + (size_t)n * DIM + l15 * 8);
            float inv = (deg > 0) ? 1.f / (float)deg : 1.f;
#pragma unroll
            for (int j = 0; j < 8; ++j)
                pk[j] = f2bf(a[j] * inv + bf2f(hres[j]));
        }
        *(u16x8*)&xs[s * 136 + l15 * 8] = pk;
    }

    // ---- phase B: fc2 MFMA from LDS ----
    const int ch = wv >> 1, rh = wv & 1;

    BF8 barr[4][4];
#pragma unroll
    for (int ct = 0; ct < 4; ++ct)
#pragma unroll
        for (int ks = 0; ks < 4; ++ks) {
            const float* wp = W2 + (size_t)(ch * 64 + ct * 16 + l15) * DIM
                                 + ks * 32 + quad * 8;
            float4 f0 = *(const float4*)wp;
            float4 f1 = *(const float4*)(wp + 4);
            u16x8 p;
            p[0] = f2bf(f0.x); p[1] = f2bf(f0.y); p[2] = f2bf(f0.z); p[3] = f2bf(f0.w);
            p[4] = f2bf(f1.x); p[5] = f2bf(f1.y); p[6] = f2bf(f1.z); p[7] = f2bf(f1.w);
            barr[ct][ks].u = p;
        }

    f32x4 acc[2][4];
#pragma unroll
    for (int ct = 0; ct < 4; ++ct) {
        float bv = b2[ch * 64 + ct * 16 + l15];
        acc[0][ct] = (f32x4){bv, bv, bv, bv};
        acc[1][ct] = (f32x4){bv, bv, bv, bv};
    }
    __syncthreads();

#pragma unroll
    for (int ks = 0; ks < 4; ++ks) {
        BF8 a0, a1;
        a0.u = *(const u16x8*)&xs[(rh * 32 +  0 + l15) * 136 + ks * 32 + quad * 8];
        a1.u = *(const u16x8*)&xs[(rh * 32 + 16 + l15) * 136 + ks * 32 + quad * 8];
#pragma unroll
        for (int ct = 0; ct < 4; ++ct) {
            acc[0][ct] = __builtin_amdgcn_mfma_f32_16x16x32_bf16(
                a0.b, barr[ct][ks].b, acc[0][ct], 0, 0, 0);
            acc[1][ct] = __builtin_amdgcn_mfma_f32_16x16x32_bf16(
                a1.b, barr[ct][ks].b, acc[1][ct], 0, 0, 0);
        }
    }

#pragma unroll
    for (int rt = 0; rt < 2; ++rt)
#pragma unroll
        for (int i = 0; i < 4; ++i) {
            int row = row0 + rh * 32 + rt * 16 + quad * 4 + i;
            if (row < N_NODES) {
#pragma unroll
                for (int ct = 0; ct < 4; ++ct) {
                    int col = ch * 64 + ct * 16 + l15;
                    out[(size_t)row * DIM + col] = acc[rt][ct][i];
                }
            }
        }
}

extern "C" void kernel_launch(void* const* d_in, const int* in_sizes, int n_in,
                              void* d_out, int out_size, void* d_ws, size_t ws_size,
                              hipStream_t stream)
{
    const float* x  = (const float*)d_in[0];
    const int*   ei = (const int*)d_in[1];   // [2][E] int32
    const float* W1 = (const float*)d_in[2];
    const float* b1 = (const float*)d_in[3];
    const float* W2 = (const float*)d_in[4];
    const float* b2 = (const float*)d_in[5];
    float* out = (float*)d_out;

    const int* esrc = ei;
    const int* edst = ei + N_EDGES;

    char* ws = (char*)d_ws;
    size_t off = 0;
    u16*  h       = (u16*)(ws + off);  off += (size_t)N_NODES * DIM * 2;   // 12.8 MB
    int*  head    = (int*)(ws + off);  off += (size_t)N_NODES * 4;         // 200 KB
    int2* pairbuf = (int2*)(ws + off); off += (size_t)N_EDGES * 8;         // 3.2 MB

    // head = -1 everywhere (0xFF byte pattern)
    hipMemsetAsync(head, 0xFF, (size_t)N_NODES * 4, stream);

    build_fc1_kernel<<<BUCKET_BLK + FC1_BLK, 256, 0, stream>>>(
        esrc, edst, head, pairbuf, x, W1, b1, h);
    agg_fc2_kernel<<<FC1_BLK, 256, 0, stream>>>(
        head, pairbuf, h, W2, b2, out);
}

// Round 4
// 187.178 us; speedup vs baseline: 1.0558x; 1.0558x over previous
//
#include <hip/hip_runtime.h>

#define N_NODES 50000
#define N_EDGES 400000
#define DIM 128
#define N_SCAN_BLK ((N_NODES + 255) / 256)   // 196
#define BUCKET_BLK ((N_EDGES + 255) / 256)   // 1563
#define FC1_BLK ((N_NODES + 63) / 64)        // 782
#define AGG_BLK (N_NODES / 16)               // 3125 (exact)

typedef unsigned short u16;
typedef unsigned int   u32;
typedef __bf16 v8bf  __attribute__((ext_vector_type(8)));
typedef float  f32x4 __attribute__((ext_vector_type(4)));
typedef u16    u16x8 __attribute__((ext_vector_type(8)));

union BF8 { u16x8 u; v8bf b; };

__device__ __forceinline__ float bf2f(u16 u) {
    union { u32 i; float f; } v; v.i = ((u32)u) << 16; return v.f;
}
__device__ __forceinline__ u16 f2bf(float f) {
    union { float f; u32 i; } v; v.f = f; u32 u = v.i;
    return (u16)((u + 0x7FFFu + ((u >> 16) & 1u)) >> 16);  // RNE
}

// ---------------------------------------------------------------------------
// histogram of dst
// ---------------------------------------------------------------------------
__global__ __launch_bounds__(256) void count_kernel(
    const int* __restrict__ edst, int* __restrict__ counts)
{
    int e = blockIdx.x * 256 + threadIdx.x;
    if (e >= N_EDGES) return;
    int dst = edst[e];
    if ((unsigned)dst >= N_NODES) return;
    atomicAdd(&counts[dst], 1);
}

// ---------------------------------------------------------------------------
// ticket scan: per-256-tile local exclusive scan + atomicAdd ticket for the
// tile base. Bases are contiguous per tile but not globally monotone — fine,
// aggregate uses end = row_ptr[n] + counts[n].
// ---------------------------------------------------------------------------
__global__ __launch_bounds__(256) void scan_ticket_kernel(
    const int* __restrict__ counts, int* __restrict__ row_ptr,
    int* __restrict__ cursor, int* __restrict__ gcursor)
{
    __shared__ int tmp[256];
    __shared__ int sbase;
    const int t = threadIdx.x;
    const int i = blockIdx.x * 256 + t;
    int v = (i < N_NODES) ? counts[i] : 0;
    tmp[t] = v;
    __syncthreads();
#pragma unroll
    for (int ofs = 1; ofs < 256; ofs <<= 1) {
        int add = (t >= ofs) ? tmp[t - ofs] : 0;
        __syncthreads();
        tmp[t] += add;
        __syncthreads();
    }
    if (t == 255) sbase = atomicAdd(gcursor, tmp[255]);
    __syncthreads();
    if (i < N_NODES) {
        int r = sbase + tmp[t] - v;
        row_ptr[i] = r;
        cursor[i]  = r;
    }
}

// ---------------------------------------------------------------------------
// bucket + fc1 fused: blocks [0, BUCKET_BLK) scatter edges into CSR;
// blocks [BUCKET_BLK, +FC1_BLK) run the fc1 MFMA tile (W1 cast in-regs).
// ---------------------------------------------------------------------------
__global__ __launch_bounds__(256, 3) void bucket_fc1_kernel(
    const int* __restrict__ esrc, const int* __restrict__ edst,
    int* __restrict__ cursor, int* __restrict__ esorted,
    const float* __restrict__ x, const float* __restrict__ W1,
    const float* __restrict__ b1, u16* __restrict__ h)
{
    __shared__ u16 xs[64 * 136];
    const int bid = blockIdx.x;

    if (bid < BUCKET_BLK) {
        int e = bid * 256 + threadIdx.x;
        if (e < N_EDGES) {
            int src = esrc[e], dst = edst[e];
            if ((unsigned)src < N_NODES && (unsigned)dst < N_NODES) {
                int pos = atomicAdd(&cursor[dst], 1);
                esorted[pos] = src;
            }
        }
        return;
    }

    const int t = threadIdx.x;
    const int wave = t >> 6, lane = t & 63, quad = lane >> 4, l15 = lane & 15;
    const int ch = wave >> 1, rh = wave & 1;
    const int row0 = (bid - BUCKET_BLK) * 64;

    BF8 barr[4][4];
#pragma unroll
    for (int ct = 0; ct < 4; ++ct)
#pragma unroll
        for (int ks = 0; ks < 4; ++ks) {
            const float* wp = W1 + (size_t)(ch * 64 + ct * 16 + l15) * DIM
                                 + ks * 32 + quad * 8;
            float4 f0 = *(const float4*)wp;
            float4 f1 = *(const float4*)(wp + 4);
            u16x8 p;
            p[0] = f2bf(f0.x); p[1] = f2bf(f0.y); p[2] = f2bf(f0.z); p[3] = f2bf(f0.w);
            p[4] = f2bf(f1.x); p[5] = f2bf(f1.y); p[6] = f2bf(f1.z); p[7] = f2bf(f1.w);
            barr[ct][ks].u = p;
        }

    {
        int srow = t >> 2, k0 = (t & 3) * 32;
        int grow = row0 + srow; if (grow >= N_NODES) grow = N_NODES - 1;
        const float* xp = x + (size_t)grow * DIM + k0;
#pragma unroll
        for (int j = 0; j < 4; ++j) {
            float4 f0 = *(const float4*)(xp + j * 8);
            float4 f1 = *(const float4*)(xp + j * 8 + 4);
            u16x8 p;
            p[0] = f2bf(f0.x); p[1] = f2bf(f0.y); p[2] = f2bf(f0.z); p[3] = f2bf(f0.w);
            p[4] = f2bf(f1.x); p[5] = f2bf(f1.y); p[6] = f2bf(f1.z); p[7] = f2bf(f1.w);
            *(u16x8*)&xs[srow * 136 + k0 + j * 8] = p;
        }
    }

    f32x4 acc[2][4];
#pragma unroll
    for (int ct = 0; ct < 4; ++ct) {
        float bv = b1[ch * 64 + ct * 16 + l15];
        acc[0][ct] = (f32x4){bv, bv, bv, bv};
        acc[1][ct] = (f32x4){bv, bv, bv, bv};
    }
    __syncthreads();

#pragma unroll
    for (int ks = 0; ks < 4; ++ks) {
        BF8 a0, a1;
        a0.u = *(const u16x8*)&xs[(rh * 32 +  0 + l15) * 136 + ks * 32 + quad * 8];
        a1.u = *(const u16x8*)&xs[(rh * 32 + 16 + l15) * 136 + ks * 32 + quad * 8];
#pragma unroll
        for (int ct = 0; ct < 4; ++ct) {
            acc[0][ct] = __builtin_amdgcn_mfma_f32_16x16x32_bf16(
                a0.b, barr[ct][ks].b, acc[0][ct], 0, 0, 0);
            acc[1][ct] = __builtin_amdgcn_mfma_f32_16x16x32_bf16(
                a1.b, barr[ct][ks].b, acc[1][ct], 0, 0, 0);
        }
    }

#pragma unroll
    for (int rt = 0; rt < 2; ++rt)
#pragma unroll
        for (int i = 0; i < 4; ++i) {
            int row = row0 + rh * 32 + rt * 16 + quad * 4 + i;
            if (row < N_NODES) {
#pragma unroll
                for (int ct = 0; ct < 4; ++ct) {
                    int col = ch * 64 + ct * 16 + l15;
                    h[(size_t)row * DIM + col] = f2bf(fmaxf(acc[rt][ct][i], 0.f));
                }
            }
        }
}

// ---------------------------------------------------------------------------
// aggregate + fc2 fused on 16-node tiles (3125 blocks for TLP).
// Phase A: quad-per-node CSR gather, 8 row-loads in flight per quad
//   (16 lanes x 16B cover a 256B row). Result -> LDS tile; z never global.
// Phase B: M=16 fc2 MFMA; each wave computes 32 output cols (8 MFMA).
// ---------------------------------------------------------------------------
__global__ __launch_bounds__(256) void agg_fc2_kernel(
    const int* __restrict__ row_ptr, const int* __restrict__ counts,
    const int* __restrict__ esorted, const u16* __restrict__ h,
    const float* __restrict__ W2, const float* __restrict__ b2,
    float* __restrict__ out)
{
    __shared__ u16 xs[16 * 136];
    const int t = threadIdx.x;
    const int wv = t >> 6, lane = t & 63, quad = lane >> 4, l15 = lane & 15;
    const int row0 = blockIdx.x * 16;

    // ---- phase A: CSR gather, quad per node (s = wv*4 + quad) ----
    {
        const int s = wv * 4 + quad;
        const int n = row0 + s;                 // always < N_NODES (50000 = 3125*16)
        const int start = row_ptr[n];
        const int deg   = counts[n];
        const int end   = start + deg;

        float a[8];
#pragma unroll
        for (int j = 0; j < 8; ++j) a[j] = 0.f;

        int e = start;
        for (; e + 8 <= end; e += 8) {
            int s0 = esorted[e + 0], s1 = esorted[e + 1];
            int s2 = esorted[e + 2], s3 = esorted[e + 3];
            int s4 = esorted[e + 4], s5 = esorted[e + 5];
            int s6 = esorted[e + 6], s7 = esorted[e + 7];
            u16x8 v0 = *(const u16x8*)(h + (size_t)s0 * DIM + l15 * 8);
            u16x8 v1 = *(const u16x8*)(h + (size_t)s1 * DIM + l15 * 8);
            u16x8 v2 = *(const u16x8*)(h + (size_t)s2 * DIM + l15 * 8);
            u16x8 v3 = *(const u16x8*)(h + (size_t)s3 * DIM + l15 * 8);
            u16x8 v4 = *(const u16x8*)(h + (size_t)s4 * DIM + l15 * 8);
            u16x8 v5 = *(const u16x8*)(h + (size_t)s5 * DIM + l15 * 8);
            u16x8 v6 = *(const u16x8*)(h + (size_t)s6 * DIM + l15 * 8);
            u16x8 v7 = *(const u16x8*)(h + (size_t)s7 * DIM + l15 * 8);
#pragma unroll
            for (int j = 0; j < 8; ++j) {
                a[j] += bf2f(v0[j]); a[j] += bf2f(v1[j]);
                a[j] += bf2f(v2[j]); a[j] += bf2f(v3[j]);
                a[j] += bf2f(v4[j]); a[j] += bf2f(v5[j]);
                a[j] += bf2f(v6[j]); a[j] += bf2f(v7[j]);
            }
        }
        for (; e + 4 <= end; e += 4) {
            int s0 = esorted[e + 0], s1 = esorted[e + 1];
            int s2 = esorted[e + 2], s3 = esorted[e + 3];
            u16x8 v0 = *(const u16x8*)(h + (size_t)s0 * DIM + l15 * 8);
            u16x8 v1 = *(const u16x8*)(h + (size_t)s1 * DIM + l15 * 8);
            u16x8 v2 = *(const u16x8*)(h + (size_t)s2 * DIM + l15 * 8);
            u16x8 v3 = *(const u16x8*)(h + (size_t)s3 * DIM + l15 * 8);
#pragma unroll
            for (int j = 0; j < 8; ++j) {
                a[j] += bf2f(v0[j]); a[j] += bf2f(v1[j]);
                a[j] += bf2f(v2[j]); a[j] += bf2f(v3[j]);
            }
        }
        for (; e < end; ++e) {
            u16x8 v = *(const u16x8*)(h + (size_t)esorted[e] * DIM + l15 * 8);
#pragma unroll
            for (int j = 0; j < 8; ++j) a[j] += bf2f(v[j]);
        }

        u16x8 hres = *(const u16x8*)(h + (size_t)n * DIM + l15 * 8);
        float inv = (deg > 0) ? 1.f / (float)deg : 1.f;
        u16x8 pk;
#pragma unroll
        for (int j = 0; j < 8; ++j)
            pk[j] = f2bf(a[j] * inv + bf2f(hres[j]));
        *(u16x8*)&xs[s * 136 + l15 * 8] = pk;
    }

    // ---- phase B: fc2 MFMA from LDS (wave wv covers cols [wv*32, wv*32+32)) ----
    BF8 barr[2][4];
#pragma unroll
    for (int ct = 0; ct < 2; ++ct)
#pragma unroll
        for (int ks = 0; ks < 4; ++ks) {
            const float* wp = W2 + (size_t)(wv * 32 + ct * 16 + l15) * DIM
                                 + ks * 32 + quad * 8;
            float4 f0 = *(const float4*)wp;
            float4 f1 = *(const float4*)(wp + 4);
            u16x8 p;
            p[0] = f2bf(f0.x); p[1] = f2bf(f0.y); p[2] = f2bf(f0.z); p[3] = f2bf(f0.w);
            p[4] = f2bf(f1.x); p[5] = f2bf(f1.y); p[6] = f2bf(f1.z); p[7] = f2bf(f1.w);
            barr[ct][ks].u = p;
        }

    f32x4 acc[2];
#pragma unroll
    for (int ct = 0; ct < 2; ++ct) {
        float bv = b2[wv * 32 + ct * 16 + l15];
        acc[ct] = (f32x4){bv, bv, bv, bv};
    }
    __syncthreads();

#pragma unroll
    for (int ks = 0; ks < 4; ++ks) {
        BF8 a0;
        a0.u = *(const u16x8*)&xs[l15 * 136 + ks * 32 + quad * 8];
#pragma unroll
        for (int ct = 0; ct < 2; ++ct) {
            acc[ct] = __builtin_amdgcn_mfma_f32_16x16x32_bf16(
                a0.b, barr[ct][ks].b, acc[ct], 0, 0, 0);
        }
    }

#pragma unroll
    for (int i = 0; i < 4; ++i) {
        int row = row0 + quad * 4 + i;
#pragma unroll
        for (int ct = 0; ct < 2; ++ct) {
            int col = wv * 32 + ct * 16 + l15;
            out[(size_t)row * DIM + col] = acc[ct][i];
        }
    }
}

extern "C" void kernel_launch(void* const* d_in, const int* in_sizes, int n_in,
                              void* d_out, int out_size, void* d_ws, size_t ws_size,
                              hipStream_t stream)
{
    const float* x  = (const float*)d_in[0];
    const int*   ei = (const int*)d_in[1];   // [2][E] int32
    const float* W1 = (const float*)d_in[2];
    const float* b1 = (const float*)d_in[3];
    const float* W2 = (const float*)d_in[4];
    const float* b2 = (const float*)d_in[5];
    float* out = (float*)d_out;

    const int* esrc = ei;
    const int* edst = ei + N_EDGES;

    char* ws = (char*)d_ws;
    size_t off = 0;
    u16* h       = (u16*)(ws + off); off += (size_t)N_NODES * DIM * 2;   // 12.8 MB
    int* counts  = (int*)(ws + off); off += (size_t)N_NODES * 4;
    int* gcursor = (int*)(ws + off); off += 4;                            // adjacent: one memset
    int* row_ptr = (int*)(ws + off); off += (size_t)N_NODES * 4;
    int* cursor  = (int*)(ws + off); off += (size_t)N_NODES * 4;
    int* esorted = (int*)(ws + off); off += (size_t)N_EDGES * 4;

    // zero counts + gcursor in one memset
    hipMemsetAsync(counts, 0, (size_t)(N_NODES + 1) * 4, stream);

    count_kernel<<<BUCKET_BLK, 256, 0, stream>>>(edst, counts);
    scan_ticket_kernel<<<N_SCAN_BLK, 256, 0, stream>>>(
        counts, row_ptr, cursor, gcursor);
    bucket_fc1_kernel<<<BUCKET_BLK + FC1_BLK, 256, 0, stream>>>(
        esrc, edst, cursor, esorted, x, W1, b1, h);
    agg_fc2_kernel<<<AGG_BLK, 256, 0, stream>>>(
        row_ptr, counts, esorted, h, W2, b2, out);
}

// Round 5
// 175.654 us; speedup vs baseline: 1.1250x; 1.0656x over previous
//
#include <hip/hip_runtime.h>

#define N_NODES 50000
#define N_EDGES 400000
#define DIM 128
#define N_SCAN_BLK ((N_NODES + 255) / 256)   // 196
#define BUCKET_BLK ((N_EDGES + 255) / 256)   // 1563
#define FC1_BLK ((N_NODES + 63) / 64)        // 782
#define AGG_BLK (N_NODES / 16)               // 3125 (exact)

typedef unsigned short u16;
typedef unsigned int   u32;
typedef __bf16 v8bf  __attribute__((ext_vector_type(8)));
typedef float  f32x4 __attribute__((ext_vector_type(4)));
typedef u16    u16x8 __attribute__((ext_vector_type(8)));

union BF8 { u16x8 u; v8bf b; };

__device__ __forceinline__ float bf2f(u16 u) {
    union { u32 i; float f; } v; v.i = ((u32)u) << 16; return v.f;
}
__device__ __forceinline__ u16 f2bf(float f) {
    union { float f; u32 i; } v; v.f = f; u32 u = v.i;
    return (u16)((u + 0x7FFFu + ((u >> 16) & 1u)) >> 16);  // RNE
}

// ---------------------------------------------------------------------------
// count + fc1 fused.
//   blocks [0, BUCKET_BLK): occ[e] = atomicAdd(&counts[dst], 1)
//     (occurrence index among same-dst edges -> later scatter is atomic-free)
//   blocks [BUCKET_BLK, +FC1_BLK): fc1 MFMA tile (depends only on x/W1, so it
//     hides under the latency-bound count pass).
// ---------------------------------------------------------------------------
__global__ __launch_bounds__(256, 3) void count_fc1_kernel(
    const int* __restrict__ esrc, const int* __restrict__ edst,
    int* __restrict__ counts, int* __restrict__ occ,
    const float* __restrict__ x, const float* __restrict__ W1,
    const float* __restrict__ b1, u16* __restrict__ h)
{
    __shared__ u16 xs[64 * 136];
    const int bid = blockIdx.x;

    if (bid < BUCKET_BLK) {
        int e = bid * 256 + threadIdx.x;
        if (e < N_EDGES) {
            int src = esrc[e], dst = edst[e];
            if ((unsigned)src < N_NODES && (unsigned)dst < N_NODES)
                occ[e] = atomicAdd(&counts[dst], 1);
        }
        return;
    }

    // ---- fc1 tile ----
    const int t = threadIdx.x;
    const int wave = t >> 6, lane = t & 63, quad = lane >> 4, l15 = lane & 15;
    const int ch = wave >> 1, rh = wave & 1;
    const int row0 = (bid - BUCKET_BLK) * 64;

    BF8 barr[4][4];
#pragma unroll
    for (int ct = 0; ct < 4; ++ct)
#pragma unroll
        for (int ks = 0; ks < 4; ++ks) {
            const float* wp = W1 + (size_t)(ch * 64 + ct * 16 + l15) * DIM
                                 + ks * 32 + quad * 8;
            float4 f0 = *(const float4*)wp;
            float4 f1 = *(const float4*)(wp + 4);
            u16x8 p;
            p[0] = f2bf(f0.x); p[1] = f2bf(f0.y); p[2] = f2bf(f0.z); p[3] = f2bf(f0.w);
            p[4] = f2bf(f1.x); p[5] = f2bf(f1.y); p[6] = f2bf(f1.z); p[7] = f2bf(f1.w);
            barr[ct][ks].u = p;
        }

    {
        int srow = t >> 2, k0 = (t & 3) * 32;
        int grow = row0 + srow; if (grow >= N_NODES) grow = N_NODES - 1;
        const float* xp = x + (size_t)grow * DIM + k0;
#pragma unroll
        for (int j = 0; j < 4; ++j) {
            float4 f0 = *(const float4*)(xp + j * 8);
            float4 f1 = *(const float4*)(xp + j * 8 + 4);
            u16x8 p;
            p[0] = f2bf(f0.x); p[1] = f2bf(f0.y); p[2] = f2bf(f0.z); p[3] = f2bf(f0.w);
            p[4] = f2bf(f1.x); p[5] = f2bf(f1.y); p[6] = f2bf(f1.z); p[7] = f2bf(f1.w);
            *(u16x8*)&xs[srow * 136 + k0 + j * 8] = p;
        }
    }

    f32x4 acc[2][4];
#pragma unroll
    for (int ct = 0; ct < 4; ++ct) {
        float bv = b1[ch * 64 + ct * 16 + l15];
        acc[0][ct] = (f32x4){bv, bv, bv, bv};
        acc[1][ct] = (f32x4){bv, bv, bv, bv};
    }
    __syncthreads();

#pragma unroll
    for (int ks = 0; ks < 4; ++ks) {
        BF8 a0, a1;
        a0.u = *(const u16x8*)&xs[(rh * 32 +  0 + l15) * 136 + ks * 32 + quad * 8];
        a1.u = *(const u16x8*)&xs[(rh * 32 + 16 + l15) * 136 + ks * 32 + quad * 8];
#pragma unroll
        for (int ct = 0; ct < 4; ++ct) {
            acc[0][ct] = __builtin_amdgcn_mfma_f32_16x16x32_bf16(
                a0.b, barr[ct][ks].b, acc[0][ct], 0, 0, 0);
            acc[1][ct] = __builtin_amdgcn_mfma_f32_16x16x32_bf16(
                a1.b, barr[ct][ks].b, acc[1][ct], 0, 0, 0);
        }
    }

#pragma unroll
    for (int rt = 0; rt < 2; ++rt)
#pragma unroll
        for (int i = 0; i < 4; ++i) {
            int row = row0 + rh * 32 + rt * 16 + quad * 4 + i;
            if (row < N_NODES) {
#pragma unroll
                for (int ct = 0; ct < 4; ++ct) {
                    int col = ch * 64 + ct * 16 + l15;
                    h[(size_t)row * DIM + col] = f2bf(fmaxf(acc[rt][ct][i], 0.f));
                }
            }
        }
}

// ---------------------------------------------------------------------------
// ticket scan: per-256-tile local exclusive scan + atomicAdd ticket for the
// tile base. Bases per tile are contiguous but not globally monotone — fine,
// aggregate uses end = row_ptr[n] + counts[n].
// ---------------------------------------------------------------------------
__global__ __launch_bounds__(256) void scan_ticket_kernel(
    const int* __restrict__ counts, int* __restrict__ row_ptr,
    int* __restrict__ gcursor)
{
    __shared__ int tmp[256];
    __shared__ int sbase;
    const int t = threadIdx.x;
    const int i = blockIdx.x * 256 + t;
    int v = (i < N_NODES) ? counts[i] : 0;
    tmp[t] = v;
    __syncthreads();
#pragma unroll
    for (int ofs = 1; ofs < 256; ofs <<= 1) {
        int add = (t >= ofs) ? tmp[t - ofs] : 0;
        __syncthreads();
        tmp[t] += add;
        __syncthreads();
    }
    if (t == 255) sbase = atomicAdd(gcursor, tmp[255]);
    __syncthreads();
    if (i < N_NODES) row_ptr[i] = sbase + tmp[t] - v;
}

// ---------------------------------------------------------------------------
// scatter: atomic-free CSR fill. pos = row_ptr[dst] + occ[e] is unique.
// ---------------------------------------------------------------------------
__global__ __launch_bounds__(256) void scatter_kernel(
    const int* __restrict__ esrc, const int* __restrict__ edst,
    const int* __restrict__ occ, const int* __restrict__ row_ptr,
    int* __restrict__ esorted)
{
    int e = blockIdx.x * 256 + threadIdx.x;
    if (e >= N_EDGES) return;
    int src = esrc[e], dst = edst[e];
    if ((unsigned)src < N_NODES && (unsigned)dst < N_NODES)
        esorted[row_ptr[dst] + occ[e]] = src;
}

// ---------------------------------------------------------------------------
// aggregate + fc2 fused on 16-node tiles (3125 blocks).
// Phase A: quad-per-node CSR gather, 8 row-loads in flight per quad
//   (16 lanes x 16B cover a 256B row). Result -> LDS tile; z never global.
// Phase B: M=16 fc2 MFMA; each wave computes 32 output cols (8 MFMA).
// ---------------------------------------------------------------------------
__global__ __launch_bounds__(256) void agg_fc2_kernel(
    const int* __restrict__ row_ptr, const int* __restrict__ counts,
    const int* __restrict__ esorted, const u16* __restrict__ h,
    const float* __restrict__ W2, const float* __restrict__ b2,
    float* __restrict__ out)
{
    __shared__ u16 xs[16 * 136];
    const int t = threadIdx.x;
    const int wv = t >> 6, lane = t & 63, quad = lane >> 4, l15 = lane & 15;
    const int row0 = blockIdx.x * 16;

    // ---- phase A: CSR gather, quad per node (s = wv*4 + quad) ----
    {
        const int s = wv * 4 + quad;
        const int n = row0 + s;                 // always < N_NODES (50000 = 3125*16)
        const int start = row_ptr[n];
        const int deg   = counts[n];
        const int end   = start + deg;

        // hoist residual row load (extra MLP during the gather loop)
        u16x8 hres = *(const u16x8*)(h + (size_t)n * DIM + l15 * 8);

        float a[8];
#pragma unroll
        for (int j = 0; j < 8; ++j) a[j] = 0.f;

        int e = start;
        for (; e + 8 <= end; e += 8) {
            int s0 = esorted[e + 0], s1 = esorted[e + 1];
            int s2 = esorted[e + 2], s3 = esorted[e + 3];
            int s4 = esorted[e + 4], s5 = esorted[e + 5];
            int s6 = esorted[e + 6], s7 = esorted[e + 7];
            u16x8 v0 = *(const u16x8*)(h + (size_t)s0 * DIM + l15 * 8);
            u16x8 v1 = *(const u16x8*)(h + (size_t)s1 * DIM + l15 * 8);
            u16x8 v2 = *(const u16x8*)(h + (size_t)s2 * DIM + l15 * 8);
            u16x8 v3 = *(const u16x8*)(h + (size_t)s3 * DIM + l15 * 8);
            u16x8 v4 = *(const u16x8*)(h + (size_t)s4 * DIM + l15 * 8);
            u16x8 v5 = *(const u16x8*)(h + (size_t)s5 * DIM + l15 * 8);
            u16x8 v6 = *(const u16x8*)(h + (size_t)s6 * DIM + l15 * 8);
            u16x8 v7 = *(const u16x8*)(h + (size_t)s7 * DIM + l15 * 8);
#pragma unroll
            for (int j = 0; j < 8; ++j) {
                a[j] += bf2f(v0[j]); a[j] += bf2f(v1[j]);
                a[j] += bf2f(v2[j]); a[j] += bf2f(v3[j]);
                a[j] += bf2f(v4[j]); a[j] += bf2f(v5[j]);
                a[j] += bf2f(v6[j]); a[j] += bf2f(v7[j]);
            }
        }
        for (; e + 4 <= end; e += 4) {
            int s0 = esorted[e + 0], s1 = esorted[e + 1];
            int s2 = esorted[e + 2], s3 = esorted[e + 3];
            u16x8 v0 = *(const u16x8*)(h + (size_t)s0 * DIM + l15 * 8);
            u16x8 v1 = *(const u16x8*)(h + (size_t)s1 * DIM + l15 * 8);
            u16x8 v2 = *(const u16x8*)(h + (size_t)s2 * DIM + l15 * 8);
            u16x8 v3 = *(const u16x8*)(h + (size_t)s3 * DIM + l15 * 8);
#pragma unroll
            for (int j = 0; j < 8; ++j) {
                a[j] += bf2f(v0[j]); a[j] += bf2f(v1[j]);
                a[j] += bf2f(v2[j]); a[j] += bf2f(v3[j]);
            }
        }
        for (; e < end; ++e) {
            u16x8 v = *(const u16x8*)(h + (size_t)esorted[e] * DIM + l15 * 8);
#pragma unroll
            for (int j = 0; j < 8; ++j) a[j] += bf2f(v[j]);
        }

        float inv = (deg > 0) ? 1.f / (float)deg : 1.f;
        u16x8 pk;
#pragma unroll
        for (int j = 0; j < 8; ++j)
            pk[j] = f2bf(a[j] * inv + bf2f(hres[j]));
        *(u16x8*)&xs[s * 136 + l15 * 8] = pk;
    }

    // ---- phase B: fc2 MFMA from LDS (wave wv covers cols [wv*32, wv*32+32)) ----
    BF8 barr[2][4];
#pragma unroll
    for (int ct = 0; ct < 2; ++ct)
#pragma unroll
        for (int ks = 0; ks < 4; ++ks) {
            const float* wp = W2 + (size_t)(wv * 32 + ct * 16 + l15) * DIM
                                 + ks * 32 + quad * 8;
            float4 f0 = *(const float4*)wp;
            float4 f1 = *(const float4*)(wp + 4);
            u16x8 p;
            p[0] = f2bf(f0.x); p[1] = f2bf(f0.y); p[2] = f2bf(f0.z); p[3] = f2bf(f0.w);
            p[4] = f2bf(f1.x); p[5] = f2bf(f1.y); p[6] = f2bf(f1.z); p[7] = f2bf(f1.w);
            barr[ct][ks].u = p;
        }

    f32x4 acc[2];
#pragma unroll
    for (int ct = 0; ct < 2; ++ct) {
        float bv = b2[wv * 32 + ct * 16 + l15];
        acc[ct] = (f32x4){bv, bv, bv, bv};
    }
    __syncthreads();

#pragma unroll
    for (int ks = 0; ks < 4; ++ks) {
        BF8 a0;
        a0.u = *(const u16x8*)&xs[l15 * 136 + ks * 32 + quad * 8];
#pragma unroll
        for (int ct = 0; ct < 2; ++ct) {
            acc[ct] = __builtin_amdgcn_mfma_f32_16x16x32_bf16(
                a0.b, barr[ct][ks].b, acc[ct], 0, 0, 0);
        }
    }

#pragma unroll
    for (int i = 0; i < 4; ++i) {
        int row = row0 + quad * 4 + i;
#pragma unroll
        for (int ct = 0; ct < 2; ++ct) {
            int col = wv * 32 + ct * 16 + l15;
            out[(size_t)row * DIM + col] = acc[ct][i];
        }
    }
}

extern "C" void kernel_launch(void* const* d_in, const int* in_sizes, int n_in,
                              void* d_out, int out_size, void* d_ws, size_t ws_size,
                              hipStream_t stream)
{
    const float* x  = (const float*)d_in[0];
    const int*   ei = (const int*)d_in[1];   // [2][E] int32
    const float* W1 = (const float*)d_in[2];
    const float* b1 = (const float*)d_in[3];
    const float* W2 = (const float*)d_in[4];
    const float* b2 = (const float*)d_in[5];
    float* out = (float*)d_out;

    const int* esrc = ei;
    const int* edst = ei + N_EDGES;

    char* ws = (char*)d_ws;
    size_t off = 0;
    u16* h       = (u16*)(ws + off); off += (size_t)N_NODES * DIM * 2;   // 12.8 MB
    int* counts  = (int*)(ws + off); off += (size_t)N_NODES * 4;
    int* gcursor = (int*)(ws + off); off += 4;                            // adjacent: one memset
    int* row_ptr = (int*)(ws + off); off += (size_t)N_NODES * 4;
    int* occ     = (int*)(ws + off); off += (size_t)N_EDGES * 4;
    int* esorted = (int*)(ws + off); off += (size_t)N_EDGES * 4;

    // zero counts + gcursor in one memset
    hipMemsetAsync(counts, 0, (size_t)(N_NODES + 1) * 4, stream);

    count_fc1_kernel<<<BUCKET_BLK + FC1_BLK, 256, 0, stream>>>(
        esrc, edst, counts, occ, x, W1, b1, h);
    scan_ticket_kernel<<<N_SCAN_BLK, 256, 0, stream>>>(
        counts, row_ptr, gcursor);
    scatter_kernel<<<BUCKET_BLK, 256, 0, stream>>>(
        esrc, edst, occ, row_ptr, esorted);
    agg_fc2_kernel<<<AGG_BLK, 256, 0, stream>>>(
        row_ptr, counts, esorted, h, W2, b2, out);
}

// Round 6
// 161.247 us; speedup vs baseline: 1.2256x; 1.0893x over previous
//
#include <hip/hip_runtime.h>

#define N_NODES 50000
#define N_EDGES 400000
#define DIM 128
#define N_SCAN_BLK ((N_NODES + 255) / 256)     // 196
#define CNT_BLK ((N_EDGES + 1023) / 1024)      // 391  (4 edges/thread)
#define FC1_BLK ((N_NODES + 63) / 64)          // 782
#define AGG_BLK (N_NODES / 16)                 // 3125 (exact)
#define PADDED_E (N_EDGES + 3 * N_NODES)       // 550000 worst-case padded CSR

typedef unsigned short u16;
typedef unsigned int   u32;
typedef __bf16 v8bf  __attribute__((ext_vector_type(8)));
typedef float  f32x4 __attribute__((ext_vector_type(4)));
typedef u16    u16x8 __attribute__((ext_vector_type(8)));

union BF8 { u16x8 u; v8bf b; };

__device__ __forceinline__ float bf2f(u16 u) {
    union { u32 i; float f; } v; v.i = ((u32)u) << 16; return v.f;
}
__device__ __forceinline__ u16 f2bf(float f) {
    union { float f; u32 i; } v; v.f = f; u32 u = v.i;
    return (u16)((u + 0x7FFFu + ((u >> 16) & 1u)) >> 16);  // RNE
}

// ---------------------------------------------------------------------------
// count + cast + fc1 fused.
//   blocks [0, CNT_BLK): 4 edges/thread, int4 loads, 4 independent
//     atomicAdds in flight; occ written as one coalesced int4.
//   blocks [CNT_BLK, +64): cast W2 -> bf16 (for agg_fc2's phase B).
//   block  [CNT_BLK+64]: zero the sentinel h row (index N_NODES).
//   blocks [CNT_BLK+65, +FC1_BLK): fc1 MFMA tile (W1 cast in-regs; hides
//     under the latency-bound count pass).
// ---------------------------------------------------------------------------
__global__ __launch_bounds__(256, 3) void count_cast_fc1_kernel(
    const int* __restrict__ esrc, const int* __restrict__ edst,
    int* __restrict__ counts, int* __restrict__ occ,
    const float* __restrict__ W2, u16* __restrict__ Wb2,
    const float* __restrict__ x, const float* __restrict__ W1,
    const float* __restrict__ b1, u16* __restrict__ h)
{
    __shared__ u16 xs[64 * 136];
    const int bid = blockIdx.x;

    if (bid < CNT_BLK) {
        int e0 = bid * 1024 + threadIdx.x * 4;
        if (e0 < N_EDGES) {                      // N_EDGES % 4 == 0
            int4 d4 = *(const int4*)(edst + e0);
            int4 o;
            o.x = atomicAdd(&counts[d4.x], 1);
            o.y = atomicAdd(&counts[d4.y], 1);
            o.z = atomicAdd(&counts[d4.z], 1);
            o.w = atomicAdd(&counts[d4.w], 1);
            *(int4*)(occ + e0) = o;
        }
        return;
    }
    if (bid < CNT_BLK + 64) {
        int i = (bid - CNT_BLK) * 256 + threadIdx.x;
        Wb2[i] = f2bf(W2[i]);                    // 64*256 == DIM*DIM
        return;
    }
    if (bid == CNT_BLK + 64) {
        // sentinel zero row at h[N_NODES]
        if (threadIdx.x < 128)
            *(u32*)(h + (size_t)N_NODES * DIM + threadIdx.x * 2) = 0u;
        return;
    }

    // ---- fc1 tile ----
    const int t = threadIdx.x;
    const int wave = t >> 6, lane = t & 63, quad = lane >> 4, l15 = lane & 15;
    const int ch = wave >> 1, rh = wave & 1;
    const int row0 = (bid - (CNT_BLK + 65)) * 64;

    BF8 barr[4][4];
#pragma unroll
    for (int ct = 0; ct < 4; ++ct)
#pragma unroll
        for (int ks = 0; ks < 4; ++ks) {
            const float* wp = W1 + (size_t)(ch * 64 + ct * 16 + l15) * DIM
                                 + ks * 32 + quad * 8;
            float4 f0 = *(const float4*)wp;
            float4 f1 = *(const float4*)(wp + 4);
            u16x8 p;
            p[0] = f2bf(f0.x); p[1] = f2bf(f0.y); p[2] = f2bf(f0.z); p[3] = f2bf(f0.w);
            p[4] = f2bf(f1.x); p[5] = f2bf(f1.y); p[6] = f2bf(f1.z); p[7] = f2bf(f1.w);
            barr[ct][ks].u = p;
        }

    {
        int srow = t >> 2, k0 = (t & 3) * 32;
        int grow = row0 + srow; if (grow >= N_NODES) grow = N_NODES - 1;
        const float* xp = x + (size_t)grow * DIM + k0;
#pragma unroll
        for (int j = 0; j < 4; ++j) {
            float4 f0 = *(const float4*)(xp + j * 8);
            float4 f1 = *(const float4*)(xp + j * 8 + 4);
            u16x8 p;
            p[0] = f2bf(f0.x); p[1] = f2bf(f0.y); p[2] = f2bf(f0.z); p[3] = f2bf(f0.w);
            p[4] = f2bf(f1.x); p[5] = f2bf(f1.y); p[6] = f2bf(f1.z); p[7] = f2bf(f1.w);
            *(u16x8*)&xs[srow * 136 + k0 + j * 8] = p;
        }
    }

    f32x4 acc[2][4];
#pragma unroll
    for (int ct = 0; ct < 4; ++ct) {
        float bv = b1[ch * 64 + ct * 16 + l15];
        acc[0][ct] = (f32x4){bv, bv, bv, bv};
        acc[1][ct] = (f32x4){bv, bv, bv, bv};
    }
    __syncthreads();

#pragma unroll
    for (int ks = 0; ks < 4; ++ks) {
        BF8 a0, a1;
        a0.u = *(const u16x8*)&xs[(rh * 32 +  0 + l15) * 136 + ks * 32 + quad * 8];
        a1.u = *(const u16x8*)&xs[(rh * 32 + 16 + l15) * 136 + ks * 32 + quad * 8];
#pragma unroll
        for (int ct = 0; ct < 4; ++ct) {
            acc[0][ct] = __builtin_amdgcn_mfma_f32_16x16x32_bf16(
                a0.b, barr[ct][ks].b, acc[0][ct], 0, 0, 0);
            acc[1][ct] = __builtin_amdgcn_mfma_f32_16x16x32_bf16(
                a1.b, barr[ct][ks].b, acc[1][ct], 0, 0, 0);
        }
    }

#pragma unroll
    for (int rt = 0; rt < 2; ++rt)
#pragma unroll
        for (int i = 0; i < 4; ++i) {
            int row = row0 + rh * 32 + rt * 16 + quad * 4 + i;
            if (row < N_NODES) {
#pragma unroll
                for (int ct = 0; ct < 4; ++ct) {
                    int col = ch * 64 + ct * 16 + l15;
                    h[(size_t)row * DIM + col] = f2bf(fmaxf(acc[rt][ct][i], 0.f));
                }
            }
        }
}

// ---------------------------------------------------------------------------
// ticket scan over PADDED row sizes ((deg+3)&~3) + atomic ticket per tile.
// Also pre-fills each row's pad slots with the sentinel index N_NODES
// (h[N_NODES] is a zero row -> pads contribute exact 0 to the sum).
// Bases are contiguous per tile but not globally monotone — fine, aggregate
// uses deg = counts[n] for the mean and padded length for the loop.
// ---------------------------------------------------------------------------
__global__ __launch_bounds__(256) void scan_ticket_kernel(
    const int* __restrict__ counts, int* __restrict__ row_ptr,
    int* __restrict__ gcursor, int* __restrict__ esorted)
{
    __shared__ int tmp[256];
    __shared__ int sbase;
    const int t = threadIdx.x;
    const int i = blockIdx.x * 256 + t;
    int deg = (i < N_NODES) ? counts[i] : 0;
    int p = (deg + 3) & ~3;
    tmp[t] = p;
    __syncthreads();
#pragma unroll
    for (int ofs = 1; ofs < 256; ofs <<= 1) {
        int add = (t >= ofs) ? tmp[t - ofs] : 0;
        __syncthreads();
        tmp[t] += add;
        __syncthreads();
    }
    if (t == 255) sbase = atomicAdd(gcursor, tmp[255]);
    __syncthreads();
    if (i < N_NODES) {
        int r = sbase + tmp[t] - p;
        row_ptr[i] = r;
        for (int k = deg; k < p; ++k) esorted[r + k] = N_NODES;  // <=3 writes
    }
}

// ---------------------------------------------------------------------------
// scatter: atomic-free CSR fill, 4 edges/thread, int4 loads.
// pos = row_ptr[dst] + occ[e] is unique.
// ---------------------------------------------------------------------------
__global__ __launch_bounds__(256) void scatter_kernel(
    const int* __restrict__ esrc, const int* __restrict__ edst,
    const int* __restrict__ occ, const int* __restrict__ row_ptr,
    int* __restrict__ esorted)
{
    int e0 = blockIdx.x * 1024 + threadIdx.x * 4;
    if (e0 >= N_EDGES) return;
    int4 s4 = *(const int4*)(esrc + e0);
    int4 d4 = *(const int4*)(edst + e0);
    int4 o4 = *(const int4*)(occ + e0);
    esorted[row_ptr[d4.x] + o4.x] = s4.x;
    esorted[row_ptr[d4.y] + o4.y] = s4.y;
    esorted[row_ptr[d4.z] + o4.z] = s4.z;
    esorted[row_ptr[d4.w] + o4.w] = s4.w;
}

// ---------------------------------------------------------------------------
// aggregate + fc2 fused on 16-node tiles (3125 blocks).
// Phase A: quad-per-node padded-CSR gather. Indices load as aligned int4
//   (rows padded to x4 with the zero-row sentinel), 8 row-loads in flight.
//   Result -> LDS tile; z never touches global.
// Phase B: M=16 fc2 MFMA from LDS; W2 pre-cast bf16 (no in-reg f2bf).
// ---------------------------------------------------------------------------
__global__ __launch_bounds__(256) void agg_fc2_kernel(
    const int* __restrict__ row_ptr, const int* __restrict__ counts,
    const int* __restrict__ esorted, const u16* __restrict__ h,
    const u16* __restrict__ Wb2, const float* __restrict__ b2,
    float* __restrict__ out)
{
    __shared__ u16 xs[16 * 136];
    const int t = threadIdx.x;
    const int wv = t >> 6, lane = t & 63, quad = lane >> 4, l15 = lane & 15;
    const int row0 = blockIdx.x * 16;

    // ---- phase A: padded CSR gather, quad per node ----
    {
        const int s = wv * 4 + quad;
        const int n = row0 + s;                 // always < N_NODES
        const int start = row_ptr[n];           // multiple of 4
        const int deg   = counts[n];
        const int plen  = (deg + 3) & ~3;       // padded length

        u16x8 hres = *(const u16x8*)(h + (size_t)n * DIM + l15 * 8);

        float a[8];
#pragma unroll
        for (int j = 0; j < 8; ++j) a[j] = 0.f;

        const int* ep = esorted + start;
        int k = 0;
        for (; k + 8 <= plen; k += 8) {
            int4 ia = *(const int4*)(ep + k);
            int4 ib = *(const int4*)(ep + k + 4);
            u16x8 v0 = *(const u16x8*)(h + (size_t)ia.x * DIM + l15 * 8);
            u16x8 v1 = *(const u16x8*)(h + (size_t)ia.y * DIM + l15 * 8);
            u16x8 v2 = *(const u16x8*)(h + (size_t)ia.z * DIM + l15 * 8);
            u16x8 v3 = *(const u16x8*)(h + (size_t)ia.w * DIM + l15 * 8);
            u16x8 v4 = *(const u16x8*)(h + (size_t)ib.x * DIM + l15 * 8);
            u16x8 v5 = *(const u16x8*)(h + (size_t)ib.y * DIM + l15 * 8);
            u16x8 v6 = *(const u16x8*)(h + (size_t)ib.z * DIM + l15 * 8);
            u16x8 v7 = *(const u16x8*)(h + (size_t)ib.w * DIM + l15 * 8);
#pragma unroll
            for (int j = 0; j < 8; ++j) {
                a[j] += bf2f(v0[j]); a[j] += bf2f(v1[j]);
                a[j] += bf2f(v2[j]); a[j] += bf2f(v3[j]);
                a[j] += bf2f(v4[j]); a[j] += bf2f(v5[j]);
                a[j] += bf2f(v6[j]); a[j] += bf2f(v7[j]);
            }
        }
        if (k < plen) {                          // exactly 4 remain
            int4 ia = *(const int4*)(ep + k);
            u16x8 v0 = *(const u16x8*)(h + (size_t)ia.x * DIM + l15 * 8);
            u16x8 v1 = *(const u16x8*)(h + (size_t)ia.y * DIM + l15 * 8);
            u16x8 v2 = *(const u16x8*)(h + (size_t)ia.z * DIM + l15 * 8);
            u16x8 v3 = *(const u16x8*)(h + (size_t)ia.w * DIM + l15 * 8);
#pragma unroll
            for (int j = 0; j < 8; ++j) {
                a[j] += bf2f(v0[j]); a[j] += bf2f(v1[j]);
                a[j] += bf2f(v2[j]); a[j] += bf2f(v3[j]);
            }
        }

        float inv = (deg > 0) ? 1.f / (float)deg : 1.f;
        u16x8 pk;
#pragma unroll
        for (int j = 0; j < 8; ++j)
            pk[j] = f2bf(a[j] * inv + bf2f(hres[j]));
        *(u16x8*)&xs[s * 136 + l15 * 8] = pk;
    }

    // ---- phase B: fc2 MFMA from LDS (wave wv covers cols [wv*32, wv*32+32)) ----
    BF8 barr[2][4];
#pragma unroll
    for (int ct = 0; ct < 2; ++ct)
#pragma unroll
        for (int ks = 0; ks < 4; ++ks)
            barr[ct][ks].u = *(const u16x8*)(
                Wb2 + (size_t)(wv * 32 + ct * 16 + l15) * DIM + ks * 32 + quad * 8);

    f32x4 acc[2];
#pragma unroll
    for (int ct = 0; ct < 2; ++ct) {
        float bv = b2[wv * 32 + ct * 16 + l15];
        acc[ct] = (f32x4){bv, bv, bv, bv};
    }
    __syncthreads();

#pragma unroll
    for (int ks = 0; ks < 4; ++ks) {
        BF8 a0;
        a0.u = *(const u16x8*)&xs[l15 * 136 + ks * 32 + quad * 8];
#pragma unroll
        for (int ct = 0; ct < 2; ++ct) {
            acc[ct] = __builtin_amdgcn_mfma_f32_16x16x32_bf16(
                a0.b, barr[ct][ks].b, acc[ct], 0, 0, 0);
        }
    }

#pragma unroll
    for (int i = 0; i < 4; ++i) {
        int row = row0 + quad * 4 + i;
#pragma unroll
        for (int ct = 0; ct < 2; ++ct) {
            int col = wv * 32 + ct * 16 + l15;
            out[(size_t)row * DIM + col] = acc[ct][i];
        }
    }
}

extern "C" void kernel_launch(void* const* d_in, const int* in_sizes, int n_in,
                              void* d_out, int out_size, void* d_ws, size_t ws_size,
                              hipStream_t stream)
{
    const float* x  = (const float*)d_in[0];
    const int*   ei = (const int*)d_in[1];   // [2][E] int32
    const float* W1 = (const float*)d_in[2];
    const float* b1 = (const float*)d_in[3];
    const float* W2 = (const float*)d_in[4];
    const float* b2 = (const float*)d_in[5];
    float* out = (float*)d_out;

    const int* esrc = ei;
    const int* edst = ei + N_EDGES;

    char* ws = (char*)d_ws;
    size_t off = 0;
    u16* h       = (u16*)(ws + off); off += (size_t)(N_NODES + 1) * DIM * 2; // +sentinel row
    u16* Wb2     = (u16*)(ws + off); off += (size_t)DIM * DIM * 2;
    int* counts  = (int*)(ws + off); off += (size_t)N_NODES * 4;
    int* gcursor = (int*)(ws + off); off += 4;                               // adjacent: one memset
    int* row_ptr = (int*)(ws + off); off += (size_t)N_NODES * 4;
    int* occ     = (int*)(ws + off); off += (size_t)N_EDGES * 4;
    int* esorted = (int*)(ws + off); off += (size_t)PADDED_E * 4;

    // zero counts + gcursor in one memset
    hipMemsetAsync(counts, 0, (size_t)(N_NODES + 1) * 4, stream);

    count_cast_fc1_kernel<<<CNT_BLK + 65 + FC1_BLK, 256, 0, stream>>>(
        esrc, edst, counts, occ, W2, Wb2, x, W1, b1, h);
    scan_ticket_kernel<<<N_SCAN_BLK, 256, 0, stream>>>(
        counts, row_ptr, gcursor, esorted);
    scatter_kernel<<<CNT_BLK, 256, 0, stream>>>(
        esrc, edst, occ, row_ptr, esorted);
    agg_fc2_kernel<<<AGG_BLK, 256, 0, stream>>>(
        row_ptr, counts, esorted, h, Wb2, b2, out);
}

// Round 7
// 157.177 us; speedup vs baseline: 1.2573x; 1.0259x over previous
//
#include <hip/hip_runtime.h>

#define N_NODES 50000
#define N_EDGES 400000
#define DIM 128
#define N_SCAN_BLK ((N_NODES + 255) / 256)     // 196
#define CNT_BLK ((N_EDGES + 2047) / 2048)      // 196  (8 edges/thread)
#define FC1_BLK ((N_NODES + 63) / 64)          // 782
#define AGG_BLK ((N_NODES + 31) / 32)          // 1563 (32 nodes/block)
#define PADDED_E (N_EDGES + 3 * N_NODES)       // 550000 worst-case padded CSR

typedef unsigned short u16;
typedef unsigned int   u32;
typedef __bf16 v8bf  __attribute__((ext_vector_type(8)));
typedef float  f32x4 __attribute__((ext_vector_type(4)));
typedef u16    u16x8 __attribute__((ext_vector_type(8)));

union BF8 { u16x8 u; v8bf b; };

__device__ __forceinline__ float bf2f(u16 u) {
    union { u32 i; float f; } v; v.i = ((u32)u) << 16; return v.f;
}
__device__ __forceinline__ u16 f2bf(float f) {
    union { float f; u32 i; } v; v.f = f; u32 u = v.i;
    return (u16)((u + 0x7FFFu + ((u >> 16) & 1u)) >> 16);  // RNE
}

// ---------------------------------------------------------------------------
// count + cast + fc1 fused.
//   blocks [0, CNT_BLK): 8 edges/thread, 2x int4 loads, 8 independent
//     atomicAdds in flight; occ written as two coalesced int4.
//   blocks [CNT_BLK, +64): cast W2 -> bf16 (for agg_fc2's phase B).
//   block  [CNT_BLK+64]: zero the sentinel h row (index N_NODES).
//   blocks [CNT_BLK+65, +FC1_BLK): fc1 MFMA tile (W1 cast in-regs; hides
//     under the latency-bound count pass).
// ---------------------------------------------------------------------------
__global__ __launch_bounds__(256, 3) void count_cast_fc1_kernel(
    const int* __restrict__ esrc, const int* __restrict__ edst,
    int* __restrict__ counts, int* __restrict__ occ,
    const float* __restrict__ W2, u16* __restrict__ Wb2,
    const float* __restrict__ x, const float* __restrict__ W1,
    const float* __restrict__ b1, u16* __restrict__ h)
{
    __shared__ u16 xs[64 * 136];
    const int bid = blockIdx.x;

    if (bid < CNT_BLK) {
        int e0 = bid * 2048 + threadIdx.x * 8;
        if (e0 + 8 <= N_EDGES) {
            int4 da = *(const int4*)(edst + e0);
            int4 db = *(const int4*)(edst + e0 + 4);
            int4 oa, ob;
            oa.x = atomicAdd(&counts[da.x], 1);
            oa.y = atomicAdd(&counts[da.y], 1);
            oa.z = atomicAdd(&counts[da.z], 1);
            oa.w = atomicAdd(&counts[da.w], 1);
            ob.x = atomicAdd(&counts[db.x], 1);
            ob.y = atomicAdd(&counts[db.y], 1);
            ob.z = atomicAdd(&counts[db.z], 1);
            ob.w = atomicAdd(&counts[db.w], 1);
            *(int4*)(occ + e0)     = oa;
            *(int4*)(occ + e0 + 4) = ob;
        } else if (e0 < N_EDGES) {
            for (int j = 0; j < 8 && e0 + j < N_EDGES; ++j)
                occ[e0 + j] = atomicAdd(&counts[edst[e0 + j]], 1);
        }
        return;
    }
    if (bid < CNT_BLK + 64) {
        int i = (bid - CNT_BLK) * 256 + threadIdx.x;
        Wb2[i] = f2bf(W2[i]);                    // 64*256 == DIM*DIM
        return;
    }
    if (bid == CNT_BLK + 64) {
        // sentinel zero row at h[N_NODES]
        if (threadIdx.x < 128)
            *(u32*)(h + (size_t)N_NODES * DIM + threadIdx.x * 2) = 0u;
        return;
    }

    // ---- fc1 tile ----
    const int t = threadIdx.x;
    const int wave = t >> 6, lane = t & 63, quad = lane >> 4, l15 = lane & 15;
    const int ch = wave >> 1, rh = wave & 1;
    const int row0 = (bid - (CNT_BLK + 65)) * 64;

    BF8 barr[4][4];
#pragma unroll
    for (int ct = 0; ct < 4; ++ct)
#pragma unroll
        for (int ks = 0; ks < 4; ++ks) {
            const float* wp = W1 + (size_t)(ch * 64 + ct * 16 + l15) * DIM
                                 + ks * 32 + quad * 8;
            float4 f0 = *(const float4*)wp;
            float4 f1 = *(const float4*)(wp + 4);
            u16x8 p;
            p[0] = f2bf(f0.x); p[1] = f2bf(f0.y); p[2] = f2bf(f0.z); p[3] = f2bf(f0.w);
            p[4] = f2bf(f1.x); p[5] = f2bf(f1.y); p[6] = f2bf(f1.z); p[7] = f2bf(f1.w);
            barr[ct][ks].u = p;
        }

    {
        int srow = t >> 2, k0 = (t & 3) * 32;
        int grow = row0 + srow; if (grow >= N_NODES) grow = N_NODES - 1;
        const float* xp = x + (size_t)grow * DIM + k0;
#pragma unroll
        for (int j = 0; j < 4; ++j) {
            float4 f0 = *(const float4*)(xp + j * 8);
            float4 f1 = *(const float4*)(xp + j * 8 + 4);
            u16x8 p;
            p[0] = f2bf(f0.x); p[1] = f2bf(f0.y); p[2] = f2bf(f0.z); p[3] = f2bf(f0.w);
            p[4] = f2bf(f1.x); p[5] = f2bf(f1.y); p[6] = f2bf(f1.z); p[7] = f2bf(f1.w);
            *(u16x8*)&xs[srow * 136 + k0 + j * 8] = p;
        }
    }

    f32x4 acc[2][4];
#pragma unroll
    for (int ct = 0; ct < 4; ++ct) {
        float bv = b1[ch * 64 + ct * 16 + l15];
        acc[0][ct] = (f32x4){bv, bv, bv, bv};
        acc[1][ct] = (f32x4){bv, bv, bv, bv};
    }
    __syncthreads();

#pragma unroll
    for (int ks = 0; ks < 4; ++ks) {
        BF8 a0, a1;
        a0.u = *(const u16x8*)&xs[(rh * 32 +  0 + l15) * 136 + ks * 32 + quad * 8];
        a1.u = *(const u16x8*)&xs[(rh * 32 + 16 + l15) * 136 + ks * 32 + quad * 8];
#pragma unroll
        for (int ct = 0; ct < 4; ++ct) {
            acc[0][ct] = __builtin_amdgcn_mfma_f32_16x16x32_bf16(
                a0.b, barr[ct][ks].b, acc[0][ct], 0, 0, 0);
            acc[1][ct] = __builtin_amdgcn_mfma_f32_16x16x32_bf16(
                a1.b, barr[ct][ks].b, acc[1][ct], 0, 0, 0);
        }
    }

#pragma unroll
    for (int rt = 0; rt < 2; ++rt)
#pragma unroll
        for (int i = 0; i < 4; ++i) {
            int row = row0 + rh * 32 + rt * 16 + quad * 4 + i;
            if (row < N_NODES) {
#pragma unroll
                for (int ct = 0; ct < 4; ++ct) {
                    int col = ch * 64 + ct * 16 + l15;
                    h[(size_t)row * DIM + col] = f2bf(fmaxf(acc[rt][ct][i], 0.f));
                }
            }
        }
}

// ---------------------------------------------------------------------------
// ticket scan over PADDED row sizes ((deg+3)&~3) + atomic ticket per tile.
// Pre-fills pad slots with sentinel index N_NODES (zero h row -> exact 0).
// ---------------------------------------------------------------------------
__global__ __launch_bounds__(256) void scan_ticket_kernel(
    const int* __restrict__ counts, int* __restrict__ row_ptr,
    int* __restrict__ gcursor, int* __restrict__ esorted)
{
    __shared__ int tmp[256];
    __shared__ int sbase;
    const int t = threadIdx.x;
    const int i = blockIdx.x * 256 + t;
    int deg = (i < N_NODES) ? counts[i] : 0;
    int p = (deg + 3) & ~3;
    tmp[t] = p;
    __syncthreads();
#pragma unroll
    for (int ofs = 1; ofs < 256; ofs <<= 1) {
        int add = (t >= ofs) ? tmp[t - ofs] : 0;
        __syncthreads();
        tmp[t] += add;
        __syncthreads();
    }
    if (t == 255) sbase = atomicAdd(gcursor, tmp[255]);
    __syncthreads();
    if (i < N_NODES) {
        int r = sbase + tmp[t] - p;
        row_ptr[i] = r;
        for (int k = deg; k < p; ++k) esorted[r + k] = N_NODES;  // <=3 writes
    }
}

// ---------------------------------------------------------------------------
// scatter: atomic-free CSR fill, 8 edges/thread, int4 loads.
// pos = row_ptr[dst] + occ[e] is unique.
// ---------------------------------------------------------------------------
__global__ __launch_bounds__(256) void scatter_kernel(
    const int* __restrict__ esrc, const int* __restrict__ edst,
    const int* __restrict__ occ, const int* __restrict__ row_ptr,
    int* __restrict__ esorted)
{
    int e0 = blockIdx.x * 2048 + threadIdx.x * 8;
    if (e0 + 8 <= N_EDGES) {
        int4 sa = *(const int4*)(esrc + e0);
        int4 sb = *(const int4*)(esrc + e0 + 4);
        int4 da = *(const int4*)(edst + e0);
        int4 db = *(const int4*)(edst + e0 + 4);
        int4 oa = *(const int4*)(occ + e0);
        int4 ob = *(const int4*)(occ + e0 + 4);
        esorted[row_ptr[da.x] + oa.x] = sa.x;
        esorted[row_ptr[da.y] + oa.y] = sa.y;
        esorted[row_ptr[da.z] + oa.z] = sa.z;
        esorted[row_ptr[da.w] + oa.w] = sa.w;
        esorted[row_ptr[db.x] + ob.x] = sb.x;
        esorted[row_ptr[db.y] + ob.y] = sb.y;
        esorted[row_ptr[db.z] + ob.z] = sb.z;
        esorted[row_ptr[db.w] + ob.w] = sb.w;
    } else if (e0 < N_EDGES) {
        for (int j = 0; j < 8 && e0 + j < N_EDGES; ++j)
            esorted[row_ptr[edst[e0 + j]] + occ[e0 + j]] = esrc[e0 + j];
    }
}

// ---------------------------------------------------------------------------
// aggregate + fc2 fused on 32-node tiles (1563 blocks).
// Phase A: each quad owns TWO nodes with interleaved 4-edge batches:
//   8 independent row-gathers in flight, two independent index chains,
//   per-quad work = deg0+deg1 (variance halved -> smaller block tail).
//   Result (mean + residual) -> LDS tile; z never touches global.
// Phase B: M=32 fc2 MFMA from LDS; W2 pre-cast bf16.
// ---------------------------------------------------------------------------
__global__ __launch_bounds__(256, 6) void agg_fc2_kernel(
    const int* __restrict__ row_ptr, const int* __restrict__ counts,
    const int* __restrict__ esorted, const u16* __restrict__ h,
    const u16* __restrict__ Wb2, const float* __restrict__ b2,
    float* __restrict__ out)
{
    __shared__ u16 xs[32 * 136];
    const int t = threadIdx.x;
    const int wv = t >> 6, lane = t & 63, quad = lane >> 4, l15 = lane & 15;
    const int row0 = blockIdx.x * 32;

    // ---- phase A: two interleaved padded-CSR gathers per quad ----
    {
        const int s0 = wv * 8 + quad * 2;
        const int n0 = row0 + s0;
        const int n1 = n0 + 1;
        const bool va = (n0 < N_NODES), vb = (n1 < N_NODES);
        int start0 = 0, deg0 = 0, start1 = 0, deg1 = 0;
        if (va) { start0 = row_ptr[n0]; deg0 = counts[n0]; }
        if (vb) { start1 = row_ptr[n1]; deg1 = counts[n1]; }
        const int plen0 = (deg0 + 3) & ~3;
        const int plen1 = (deg1 + 3) & ~3;

        u16x8 hres0 = (u16x8){0,0,0,0,0,0,0,0};
        u16x8 hres1 = (u16x8){0,0,0,0,0,0,0,0};
        if (va) hres0 = *(const u16x8*)(h + (size_t)n0 * DIM + l15 * 8);
        if (vb) hres1 = *(const u16x8*)(h + (size_t)n1 * DIM + l15 * 8);

        float a0[8], a1[8];
#pragma unroll
        for (int j = 0; j < 8; ++j) { a0[j] = 0.f; a1[j] = 0.f; }

        const int* ep0 = esorted + start0;
        const int* ep1 = esorted + start1;
        int k0 = 0, k1 = 0;

        // interleaved main loop: 4 gathers per node, 8 loads in flight
        while (k0 < plen0 && k1 < plen1) {
            int4 ia = *(const int4*)(ep0 + k0);
            int4 ib = *(const int4*)(ep1 + k1);
            u16x8 v0 = *(const u16x8*)(h + (size_t)ia.x * DIM + l15 * 8);
            u16x8 v1 = *(const u16x8*)(h + (size_t)ia.y * DIM + l15 * 8);
            u16x8 v2 = *(const u16x8*)(h + (size_t)ia.z * DIM + l15 * 8);
            u16x8 v3 = *(const u16x8*)(h + (size_t)ia.w * DIM + l15 * 8);
            u16x8 w0 = *(const u16x8*)(h + (size_t)ib.x * DIM + l15 * 8);
            u16x8 w1 = *(const u16x8*)(h + (size_t)ib.y * DIM + l15 * 8);
            u16x8 w2 = *(const u16x8*)(h + (size_t)ib.z * DIM + l15 * 8);
            u16x8 w3 = *(const u16x8*)(h + (size_t)ib.w * DIM + l15 * 8);
#pragma unroll
            for (int j = 0; j < 8; ++j) {
                a0[j] += bf2f(v0[j]); a0[j] += bf2f(v1[j]);
                a0[j] += bf2f(v2[j]); a0[j] += bf2f(v3[j]);
                a1[j] += bf2f(w0[j]); a1[j] += bf2f(w1[j]);
                a1[j] += bf2f(w2[j]); a1[j] += bf2f(w3[j]);
            }
            k0 += 4; k1 += 4;
        }
        // n0 remainder, 8-deep then 4
        while (k0 + 8 <= plen0) {
            int4 ia = *(const int4*)(ep0 + k0);
            int4 ib = *(const int4*)(ep0 + k0 + 4);
            u16x8 v0 = *(const u16x8*)(h + (size_t)ia.x * DIM + l15 * 8);
            u16x8 v1 = *(const u16x8*)(h + (size_t)ia.y * DIM + l15 * 8);
            u16x8 v2 = *(const u16x8*)(h + (size_t)ia.z * DIM + l15 * 8);
            u16x8 v3 = *(const u16x8*)(h + (size_t)ia.w * DIM + l15 * 8);
            u16x8 v4 = *(const u16x8*)(h + (size_t)ib.x * DIM + l15 * 8);
            u16x8 v5 = *(const u16x8*)(h + (size_t)ib.y * DIM + l15 * 8);
            u16x8 v6 = *(const u16x8*)(h + (size_t)ib.z * DIM + l15 * 8);
            u16x8 v7 = *(const u16x8*)(h + (size_t)ib.w * DIM + l15 * 8);
#pragma unroll
            for (int j = 0; j < 8; ++j) {
                a0[j] += bf2f(v0[j]); a0[j] += bf2f(v1[j]);
                a0[j] += bf2f(v2[j]); a0[j] += bf2f(v3[j]);
                a0[j] += bf2f(v4[j]); a0[j] += bf2f(v5[j]);
                a0[j] += bf2f(v6[j]); a0[j] += bf2f(v7[j]);
            }
            k0 += 8;
        }
        if (k0 < plen0) {
            int4 ia = *(const int4*)(ep0 + k0);
            u16x8 v0 = *(const u16x8*)(h + (size_t)ia.x * DIM + l15 * 8);
            u16x8 v1 = *(const u16x8*)(h + (size_t)ia.y * DIM + l15 * 8);
            u16x8 v2 = *(const u16x8*)(h + (size_t)ia.z * DIM + l15 * 8);
            u16x8 v3 = *(const u16x8*)(h + (size_t)ia.w * DIM + l15 * 8);
#pragma unroll
            for (int j = 0; j < 8; ++j) {
                a0[j] += bf2f(v0[j]); a0[j] += bf2f(v1[j]);
                a0[j] += bf2f(v2[j]); a0[j] += bf2f(v3[j]);
            }
        }
        // n1 remainder, 8-deep then 4
        while (k1 + 8 <= plen1) {
            int4 ia = *(const int4*)(ep1 + k1);
            int4 ib = *(const int4*)(ep1 + k1 + 4);
            u16x8 v0 = *(const u16x8*)(h + (size_t)ia.x * DIM + l15 * 8);
            u16x8 v1 = *(const u16x8*)(h + (size_t)ia.y * DIM + l15 * 8);
            u16x8 v2 = *(const u16x8*)(h + (size_t)ia.z * DIM + l15 * 8);
            u16x8 v3 = *(const u16x8*)(h + (size_t)ia.w * DIM + l15 * 8);
            u16x8 v4 = *(const u16x8*)(h + (size_t)ib.x * DIM + l15 * 8);
            u16x8 v5 = *(const u16x8*)(h + (size_t)ib.y * DIM + l15 * 8);
            u16x8 v6 = *(const u16x8*)(h + (size_t)ib.z * DIM + l15 * 8);
            u16x8 v7 = *(const u16x8*)(h + (size_t)ib.w * DIM + l15 * 8);
#pragma unroll
            for (int j = 0; j < 8; ++j) {
                a1[j] += bf2f(v0[j]); a1[j] += bf2f(v1[j]);
                a1[j] += bf2f(v2[j]); a1[j] += bf2f(v3[j]);
                a1[j] += bf2f(v4[j]); a1[j] += bf2f(v5[j]);
                a1[j] += bf2f(v6[j]); a1[j] += bf2f(v7[j]);
            }
            k1 += 8;
        }
        if (k1 < plen1) {
            int4 ia = *(const int4*)(ep1 + k1);
            u16x8 v0 = *(const u16x8*)(h + (size_t)ia.x * DIM + l15 * 8);
            u16x8 v1 = *(const u16x8*)(h + (size_t)ia.y * DIM + l15 * 8);
            u16x8 v2 = *(const u16x8*)(h + (size_t)ia.z * DIM + l15 * 8);
            u16x8 v3 = *(const u16x8*)(h + (size_t)ia.w * DIM + l15 * 8);
#pragma unroll
            for (int j = 0; j < 8; ++j) {
                a1[j] += bf2f(v0[j]); a1[j] += bf2f(v1[j]);
                a1[j] += bf2f(v2[j]); a1[j] += bf2f(v3[j]);
            }
        }

        float inv0 = (deg0 > 0) ? 1.f / (float)deg0 : 1.f;
        float inv1 = (deg1 > 0) ? 1.f / (float)deg1 : 1.f;
        u16x8 pk0, pk1;
#pragma unroll
        for (int j = 0; j < 8; ++j) {
            pk0[j] = f2bf(a0[j] * inv0 + bf2f(hres0[j]));
            pk1[j] = f2bf(a1[j] * inv1 + bf2f(hres1[j]));
        }
        *(u16x8*)&xs[s0 * 136 + l15 * 8]       = pk0;
        *(u16x8*)&xs[(s0 + 1) * 136 + l15 * 8] = pk1;
    }

    // ---- phase B: M=32 fc2 MFMA from LDS (wave wv: cols [wv*32, wv*32+32)) ----
    BF8 barr[2][4];
#pragma unroll
    for (int ct = 0; ct < 2; ++ct)
#pragma unroll
        for (int ks = 0; ks < 4; ++ks)
            barr[ct][ks].u = *(const u16x8*)(
                Wb2 + (size_t)(wv * 32 + ct * 16 + l15) * DIM + ks * 32 + quad * 8);

    f32x4 acc[2][2];   // [rt][ct]
#pragma unroll
    for (int ct = 0; ct < 2; ++ct) {
        float bv = b2[wv * 32 + ct * 16 + l15];
        acc[0][ct] = (f32x4){bv, bv, bv, bv};
        acc[1][ct] = (f32x4){bv, bv, bv, bv};
    }
    __syncthreads();

#pragma unroll
    for (int ks = 0; ks < 4; ++ks) {
        BF8 A0, A1;
        A0.u = *(const u16x8*)&xs[( 0 + l15) * 136 + ks * 32 + quad * 8];
        A1.u = *(const u16x8*)&xs[(16 + l15) * 136 + ks * 32 + quad * 8];
#pragma unroll
        for (int ct = 0; ct < 2; ++ct) {
            acc[0][ct] = __builtin_amdgcn_mfma_f32_16x16x32_bf16(
                A0.b, barr[ct][ks].b, acc[0][ct], 0, 0, 0);
            acc[1][ct] = __builtin_amdgcn_mfma_f32_16x16x32_bf16(
                A1.b, barr[ct][ks].b, acc[1][ct], 0, 0, 0);
        }
    }

#pragma unroll
    for (int rt = 0; rt < 2; ++rt)
#pragma unroll
        for (int i = 0; i < 4; ++i) {
            int row = row0 + rt * 16 + quad * 4 + i;
            if (row < N_NODES) {
#pragma unroll
                for (int ct = 0; ct < 2; ++ct) {
                    int col = wv * 32 + ct * 16 + l15;
                    out[(size_t)row * DIM + col] = acc[rt][ct][i];
                }
            }
        }
}

extern "C" void kernel_launch(void* const* d_in, const int* in_sizes, int n_in,
                              void* d_out, int out_size, void* d_ws, size_t ws_size,
                              hipStream_t stream)
{
    const float* x  = (const float*)d_in[0];
    const int*   ei = (const int*)d_in[1];   // [2][E] int32
    const float* W1 = (const float*)d_in[2];
    const float* b1 = (const float*)d_in[3];
    const float* W2 = (const float*)d_in[4];
    const float* b2 = (const float*)d_in[5];
    float* out = (float*)d_out;

    const int* esrc = ei;
    const int* edst = ei + N_EDGES;

    char* ws = (char*)d_ws;
    size_t off = 0;
    u16* h       = (u16*)(ws + off); off += (size_t)(N_NODES + 1) * DIM * 2; // +sentinel row
    u16* Wb2     = (u16*)(ws + off); off += (size_t)DIM * DIM * 2;
    int* counts  = (int*)(ws + off); off += (size_t)N_NODES * 4;
    int* gcursor = (int*)(ws + off); off += 4;                               // adjacent: one memset
    int* row_ptr = (int*)(ws + off); off += (size_t)N_NODES * 4;
    int* occ     = (int*)(ws + off); off += (size_t)N_EDGES * 4;
    int* esorted = (int*)(ws + off); off += (size_t)PADDED_E * 4;

    // zero counts + gcursor in one memset
    hipMemsetAsync(counts, 0, (size_t)(N_NODES + 1) * 4, stream);

    count_cast_fc1_kernel<<<CNT_BLK + 65 + FC1_BLK, 256, 0, stream>>>(
        esrc, edst, counts, occ, W2, Wb2, x, W1, b1, h);
    scan_ticket_kernel<<<N_SCAN_BLK, 256, 0, stream>>>(
        counts, row_ptr, gcursor, esorted);
    scatter_kernel<<<CNT_BLK, 256, 0, stream>>>(
        esrc, edst, occ, row_ptr, esorted);
    agg_fc2_kernel<<<AGG_BLK, 256, 0, stream>>>(
        row_ptr, counts, esorted, h, Wb2, b2, out);
}